// Round 1
// baseline (2950.682 us; speedup 1.0000x reference)
//
#include <hip/hip_runtime.h>
#include <cmath>

#define NROWS  65536
#define DIM    512
#define KCODES 2048
#define NDTOT  33554432LL   // NROWS*DIM

#define BM 128
#define BK 128
#define DT 16
#define MARGIN 0.25f

// ---------------- kernel 1: codebook squared norms ----------------
__global__ __launch_bounds__(256) void k_wnorm(const float* __restrict__ w,
                                               float* __restrict__ wnorm) {
    int wid = threadIdx.x >> 6, lane = threadIdx.x & 63;
    int k = blockIdx.x * 4 + wid;
    const float* row = w + (size_t)k * DIM;
    float s = 0.f;
    #pragma unroll
    for (int j = 0; j < DIM / 64; ++j) { float v = row[lane + 64 * j]; s = fmaf(v, v, s); }
    #pragma unroll
    for (int off = 32; off; off >>= 1) s += __shfl_xor(s, off, 64);
    if (lane == 0) wnorm[k] = s;
}

// ---------------- kernel 2: tiled distance GEMM + top-2 argmin ----------------
// block = 256 threads (16x16), tile 128 rows x 128 codes, 8x8 micro-tile.
// rows:  r = rbase + ty*8 + i      (broadcast reads, 4 distinct LDS addrs/wave)
// codes: c = kt    + j*16 + tx     (16 distinct banks, conflict-free)
__global__ __launch_bounds__(256) void k_argmin(const float* __restrict__ x,
                                                const float* __restrict__ w,
                                                const float* __restrict__ wnorm,
                                                int* __restrict__ idxo,
                                                int* __restrict__ cand2o) {
    __shared__ float xs[BM][DT + 1];
    __shared__ float wsh[BK][DT + 1];
    const int tid = threadIdx.x;
    const int tx = tid & 15, ty = tid >> 4;
    const int rbase = blockIdx.x * BM;

    float d1[8], d2[8];
    int   i1[8], i2[8];
    #pragma unroll
    for (int i = 0; i < 8; ++i) { d1[i] = d2[i] = 3.4e38f; i1[i] = i2[i] = 0x7fffffff; }

    const int lrow = tid >> 2;        // 0..63
    const int lq   = (tid & 3) * 4;   // 0,4,8,12

    for (int kt = 0; kt < KCODES; kt += BK) {
        float acc[8][8];
        #pragma unroll
        for (int i = 0; i < 8; ++i)
            #pragma unroll
            for (int j = 0; j < 8; ++j) acc[i][j] = 0.f;

        for (int db = 0; db < DIM; db += DT) {
            float4 xv0 = *(const float4*)&x[(size_t)(rbase + lrow) * DIM + db + lq];
            float4 xv1 = *(const float4*)&x[(size_t)(rbase + lrow + 64) * DIM + db + lq];
            float4 wv0 = *(const float4*)&w[(size_t)(kt + lrow) * DIM + db + lq];
            float4 wv1 = *(const float4*)&w[(size_t)(kt + lrow + 64) * DIM + db + lq];
            __syncthreads();   // previous chunk fully consumed
            xs[lrow][lq + 0] = xv0.x; xs[lrow][lq + 1] = xv0.y;
            xs[lrow][lq + 2] = xv0.z; xs[lrow][lq + 3] = xv0.w;
            xs[lrow + 64][lq + 0] = xv1.x; xs[lrow + 64][lq + 1] = xv1.y;
            xs[lrow + 64][lq + 2] = xv1.z; xs[lrow + 64][lq + 3] = xv1.w;
            wsh[lrow][lq + 0] = wv0.x; wsh[lrow][lq + 1] = wv0.y;
            wsh[lrow][lq + 2] = wv0.z; wsh[lrow][lq + 3] = wv0.w;
            wsh[lrow + 64][lq + 0] = wv1.x; wsh[lrow + 64][lq + 1] = wv1.y;
            wsh[lrow + 64][lq + 2] = wv1.z; wsh[lrow + 64][lq + 3] = wv1.w;
            __syncthreads();
            #pragma unroll
            for (int d = 0; d < DT; ++d) {
                float xr[8], wr[8];
                #pragma unroll
                for (int i = 0; i < 8; ++i) xr[i] = xs[ty * 8 + i][d];
                #pragma unroll
                for (int j = 0; j < 8; ++j) wr[j] = wsh[j * 16 + tx][d];
                #pragma unroll
                for (int i = 0; i < 8; ++i)
                    #pragma unroll
                    for (int j = 0; j < 8; ++j) acc[i][j] = fmaf(xr[i], wr[j], acc[i][j]);
            }
        }

        // tile epilogue: distances + top-2 update
        float wn[8];
        #pragma unroll
        for (int j = 0; j < 8; ++j) wn[j] = wnorm[kt + j * 16 + tx];
        #pragma unroll
        for (int i = 0; i < 8; ++i) {
            #pragma unroll
            for (int j = 0; j < 8; ++j) {
                float dist = fmaf(-2.f, acc[i][j], wn[j]);
                int c = kt + j * 16 + tx;
                if (dist < d1[i] || (dist == d1[i] && c < i1[i])) {
                    if (d1[i] < d2[i] || (d1[i] == d2[i] && i1[i] < i2[i])) { d2[i] = d1[i]; i2[i] = i1[i]; }
                    d1[i] = dist; i1[i] = c;
                } else if (dist < d2[i] || (dist == d2[i] && c < i2[i])) {
                    d2[i] = dist; i2[i] = c;
                }
            }
        }
    }

    // butterfly top-2 merge across the 16 lanes sharing each row group
    #pragma unroll
    for (int i = 0; i < 8; ++i) {
        #pragma unroll
        for (int off = 1; off < 16; off <<= 1) {
            float od1 = __shfl_xor(d1[i], off, 16);
            int   oi1 = __shfl_xor(i1[i], off, 16);
            float od2 = __shfl_xor(d2[i], off, 16);
            int   oi2 = __shfl_xor(i2[i], off, 16);
            if (od1 < d1[i] || (od1 == d1[i] && oi1 < i1[i])) {
                float nd2; int ni2;
                if (d1[i] < od2 || (d1[i] == od2 && i1[i] < oi2)) { nd2 = d1[i]; ni2 = i1[i]; }
                else                                             { nd2 = od2;  ni2 = oi2; }
                d1[i] = od1; i1[i] = oi1; d2[i] = nd2; i2[i] = ni2;
            } else if (od1 < d2[i] || (od1 == d2[i] && oi1 < i2[i])) {
                d2[i] = od1; i2[i] = oi1;
            }
        }
    }

    if (tx == 0) {
        #pragma unroll
        for (int i = 0; i < 8; ++i) {
            int row = rbase + ty * 8 + i;
            idxo[row]   = i1[i];
            cand2o[row] = (d2[i] - d1[i] < MARGIN) ? i2[i] : -1;
        }
    }
}

// ---------------- kernel 3: fp64 refinement of near-tie rows ----------------
__global__ __launch_bounds__(256) void k_refine(const float* __restrict__ x,
                                                const float* __restrict__ w,
                                                int* __restrict__ idxo,
                                                const int* __restrict__ cand2o) {
    int wid = threadIdx.x >> 6, lane = threadIdx.x & 63;
    int n = blockIdx.x * 4 + wid;
    int c2 = cand2o[n];
    if (c2 < 0) return;
    int c1 = idxo[n];
    const float* xr = x + (size_t)n * DIM;
    const float* w1 = w + (size_t)c1 * DIM;
    const float* w2 = w + (size_t)c2 * DIM;
    double s1 = 0.0, s2 = 0.0;
    #pragma unroll
    for (int j = 0; j < DIM / 64; ++j) {
        int d = lane + 64 * j;
        double xv = (double)xr[d];
        double a = (double)w1[d], b = (double)w2[d];
        s1 += a * a - 2.0 * xv * a;
        s2 += b * b - 2.0 * xv * b;
    }
    #pragma unroll
    for (int off = 32; off; off >>= 1) { s1 += __shfl_xor(s1, off, 64); s2 += __shfl_xor(s2, off, 64); }
    if (lane == 0) {
        int winner = (s2 < s1 || (s2 == s1 && c2 < c1)) ? c2 : c1;
        idxo[n] = winner;
    }
}

// ---------------- kernel 4: gather + loss partials + histogram + index out ----------------
__global__ __launch_bounds__(256) void k_gather(const float* __restrict__ x,
                                                const float* __restrict__ w,
                                                const int* __restrict__ idxo,
                                                float* __restrict__ out,
                                                int* __restrict__ hist,
                                                float* __restrict__ lossp) {
    int wid = threadIdx.x >> 6, lane = threadIdx.x & 63;
    int n = blockIdx.x * 4 + wid;
    int c = idxo[n];
    const float* wq = w + (size_t)c * DIM;
    const float* xq = x + (size_t)n * DIM;
    float* oq = out + 1 + (size_t)n * DIM;   // quantized_st == quantized numerically
    float s = 0.f;
    #pragma unroll
    for (int j = 0; j < DIM / 64; ++j) {
        int d = j * 64 + lane;
        float qv = wq[d];
        float dv = qv - xq[d];
        oq[d] = qv;
        s = fmaf(dv, dv, s);
    }
    #pragma unroll
    for (int off = 32; off; off >>= 1) s += __shfl_xor(s, off, 64);
    if (lane == 0) {
        lossp[n] = s;
        atomicAdd(&hist[c], 1);
        out[2 + NDTOT + n] = (float)c;       // indices output (as float)
    }
}

// ---------------- kernel 5: deterministic finalize ----------------
__global__ __launch_bounds__(256) void k_finalize(const float* __restrict__ lossp,
                                                  const int* __restrict__ hist,
                                                  float* __restrict__ out) {
    __shared__ double sm[256];
    int t = threadIdx.x;
    double s = 0.0;
    for (int i = t; i < NROWS; i += 256) s += (double)lossp[i];
    sm[t] = s; __syncthreads();
    for (int off = 128; off; off >>= 1) { if (t < off) sm[t] += sm[t + off]; __syncthreads(); }
    if (t == 0) out[0] = (float)(sm[0] * 0.25 / (double)NDTOT);
    __syncthreads();
    double e = 0.0;
    for (int k = t; k < KCODES; k += 256) {
        double p = (double)hist[k] / (double)NROWS;
        e -= p * log(p + 1e-10);
    }
    sm[t] = e; __syncthreads();
    for (int off = 128; off; off >>= 1) { if (t < off) sm[t] += sm[t + off]; __syncthreads(); }
    if (t == 0) out[1 + NDTOT] = (float)exp(sm[0]);
}

extern "C" void kernel_launch(void* const* d_in, const int* in_sizes, int n_in,
                              void* d_out, int out_size, void* d_ws, size_t ws_size,
                              hipStream_t stream) {
    const float* x = (const float*)d_in[0];   // inputs [64,1024,512]
    const float* w = (const float*)d_in[1];   // codebook [2048,512]
    float* out = (float*)d_out;
    char* ws = (char*)d_ws;

    float* wnorm = (float*)ws;                              // 2048 f
    int*   idxo  = (int*)(ws + 8192);                       // 65536 i
    int*   cand2 = (int*)(ws + 8192 + 262144);              // 65536 i
    int*   hist  = (int*)(ws + 8192 + 524288);              // 2048 i
    float* lossp = (float*)(ws + 8192 + 524288 + 8192);     // 65536 f

    hipMemsetAsync(hist, 0, KCODES * sizeof(int), stream);
    k_wnorm  <<<KCODES / 4, 256, 0, stream>>>(w, wnorm);
    k_argmin <<<NROWS / BM, 256, 0, stream>>>(x, w, wnorm, idxo, cand2);
    k_refine <<<NROWS / 4, 256, 0, stream>>>(x, w, idxo, cand2);
    k_gather <<<NROWS / 4, 256, 0, stream>>>(x, w, idxo, out, hist, lossp);
    k_finalize<<<1, 256, 0, stream>>>(lossp, hist, out);
}

// Round 3
// 614.011 us; speedup vs baseline: 4.8056x; 4.8056x over previous
//
#include <hip/hip_runtime.h>
#include <cmath>

#define NROWS  65536
#define DIM    512
#define KCODES 2048
#define NDTOT  33554432LL   // NROWS*DIM
#define MARGIN 0.0625f

typedef __attribute__((ext_vector_type(8))) short short8;   // 8 bf16 = 1 MFMA operand
typedef __attribute__((ext_vector_type(4))) float f32x4;

// round-to-nearest-even float -> bf16 (bit version)
__device__ inline unsigned int f2bf(float x) {
    unsigned int u = __float_as_uint(x);
    return (u + 0x7FFFu + ((u >> 16) & 1u)) >> 16;
}

__device__ inline void gll16(const void* g, void* l) {
    __builtin_amdgcn_global_load_lds(
        (const __attribute__((address_space(1))) void*)g,
        (__attribute__((address_space(3))) void*)l, 16, 0, 0);
}

// ---------------- kernel 1: codebook squared norms (fp32 exact) ----------------
__global__ __launch_bounds__(256) void k_wnorm(const float* __restrict__ w,
                                               float* __restrict__ wnorm) {
    int wid = threadIdx.x >> 6, lane = threadIdx.x & 63;
    int k = blockIdx.x * 4 + wid;
    const float* row = w + (size_t)k * DIM;
    float s = 0.f;
    #pragma unroll
    for (int j = 0; j < DIM / 64; ++j) { float v = row[lane + 64 * j]; s = fmaf(v, v, s); }
    #pragma unroll
    for (int off = 32; off; off >>= 1) s += __shfl_xor(s, off, 64);
    if (lane == 0) wnorm[k] = s;
}

// ---------------- kernel 2: fp32 -> bf16 hi/lo planes in fragment-lane order ----------------
// tile layout (per rowblock rb of 128 rows, per ks of 32 k): 16384 bytes:
//   [plane 2][frow 8][lane 64][16B]   where lane = ((k%32)/8)*16 + (row%16),
//   frow = (row%128)/16, bytes r = k%8. Matches mfma_f32_16x16x32_bf16 A/B frags
//   (lane l holds row l&15, k = (l>>4)*8 + r).
__global__ __launch_bounds__(256) void k_prep(const float* __restrict__ src,
                                              char* __restrict__ dst) {
    long gid = (long)blockIdx.x * 256 + threadIdx.x;
    int row = (int)(gid >> 6);
    int k8  = (int)(gid & 63);           // chunk of 8 k-values
    const float4* s = (const float4*)(src + (size_t)row * DIM + k8 * 8);
    float4 v0 = s[0], v1 = s[1];
    float vv[8] = {v0.x, v0.y, v0.z, v0.w, v1.x, v1.y, v1.z, v1.w};
    unsigned int hiw[4], low[4];
    #pragma unroll
    for (int j = 0; j < 4; ++j) {
        unsigned int h0 = f2bf(vv[2*j]), h1 = f2bf(vv[2*j+1]);
        float hf0 = __uint_as_float(h0 << 16), hf1 = __uint_as_float(h1 << 16);
        unsigned int l0 = f2bf(vv[2*j] - hf0), l1 = f2bf(vv[2*j+1] - hf1);
        hiw[j] = h0 | (h1 << 16);
        low[j] = l0 | (l1 << 16);
    }
    int rb = row >> 7, frow = (row >> 4) & 7;
    int ks = k8 >> 2, sub = k8 & 3;
    int l  = sub * 16 + (row & 15);
    size_t off = (size_t)(rb * 16 + ks) * 16384 + (size_t)frow * 1024 + (size_t)l * 16;
    *(uint4*)(dst + off)        = make_uint4(hiw[0], hiw[1], hiw[2], hiw[3]);
    *(uint4*)(dst + off + 8192) = make_uint4(low[0], low[1], low[2], low[3]);
}

// ---------------- kernel 3: split-bf16 MFMA GEMM + fused top-2 argmin ----------------
// 512 blocks (1 per 128-row block, 2 resident/CU at 64KB LDS), 4 waves of
// 64x64 output, cb-outer (16 x 128 codes), ks-inner (16 x K=32).
// BOTH A(rb,ks) and B(cb,ks) are staged every step (2-phase dbuf pipeline) —
// round-2's "A persists across cb" was wrong: 16 ks-tiles can't live in 2 bufs.
__global__ __launch_bounds__(256, 2) void k_gemm(const char* __restrict__ xp,
                                                 const char* __restrict__ wp,
                                                 const float* __restrict__ wnorm,
                                                 int* __restrict__ idxo,
                                                 int* __restrict__ cand2o) {
    __shared__ char smem[65536];   // As[2] @0,16384 ; Bs[2] @32768,49152
    const int tid = threadIdx.x;
    const int lane = tid & 63;
    const int wid = tid >> 6;
    const int wr = wid >> 1, wc = wid & 1;
    const int rb = blockIdx.x;
    const char* xsrc = xp + (size_t)rb * (16 * 16384);

    f32x4 acc[4][4];
    #pragma unroll
    for (int i = 0; i < 4; ++i)
        #pragma unroll
        for (int j = 0; j < 4; ++j) acc[i][j] = (f32x4){0.f, 0.f, 0.f, 0.f};

    float d1[16], d2[16]; int i1[16], i2[16];
    #pragma unroll
    for (int s = 0; s < 16; ++s) { d1[s] = d2[s] = 3.4e38f; i1[s] = i2[s] = 0; }

    auto STAGE = [&](int t) {
        int cb = t >> 4, ks = t & 15, p = t & 1;
        const char* bsrc = wp + (size_t)(cb * 16 + ks) * 16384;
        const char* asrc = xsrc + (size_t)ks * 16384;
        char* bdst = smem + 32768 + p * 16384;
        char* adst = smem + p * 16384;
        #pragma unroll
        for (int i = 0; i < 4; ++i) {
            int c = wid * 4 + i;   // 16 chunks of 1024B each, 4 per wave
            gll16(bsrc + c * 1024 + lane * 16, bdst + c * 1024);
            gll16(asrc + c * 1024 + lane * 16, adst + c * 1024);
        }
    };

    auto COMPUTE = [&](int t) {
        int p = t & 1;
        const char* A = smem + p * 16384;
        const char* B = smem + 32768 + p * 16384;
        short8 ah[4], al[4];
        #pragma unroll
        for (int fr = 0; fr < 4; ++fr) {
            int frow = wr * 4 + fr;
            ah[fr] = *(const short8*)(A + frow * 1024 + lane * 16);
            al[fr] = *(const short8*)(A + 8192 + frow * 1024 + lane * 16);
        }
        #pragma unroll
        for (int fc = 0; fc < 4; ++fc) {
            int fcol = wc * 4 + fc;
            short8 bh = *(const short8*)(B + fcol * 1024 + lane * 16);
            short8 bl = *(const short8*)(B + 8192 + fcol * 1024 + lane * 16);
            #pragma unroll
            for (int fr = 0; fr < 4; ++fr) {
                acc[fr][fc] = __builtin_amdgcn_mfma_f32_16x16x32_bf16(ah[fr], bh, acc[fr][fc], 0, 0, 0);
                acc[fr][fc] = __builtin_amdgcn_mfma_f32_16x16x32_bf16(ah[fr], bl, acc[fr][fc], 0, 0, 0);
                acc[fr][fc] = __builtin_amdgcn_mfma_f32_16x16x32_bf16(al[fr], bh, acc[fr][fc], 0, 0, 0);
            }
        }
    };

    auto EPILOGUE = [&](int cb) {
        #pragma unroll
        for (int fc = 0; fc < 4; ++fc) {
            int col = cb * 128 + wc * 64 + fc * 16 + (lane & 15);
            float wn = wnorm[col];
            #pragma unroll
            for (int fr = 0; fr < 4; ++fr) {
                #pragma unroll
                for (int reg = 0; reg < 4; ++reg) {
                    float dist = fmaf(-2.f, acc[fr][fc][reg], wn);
                    int s = fr * 4 + reg;
                    if (dist < d1[s]) { d2[s] = d1[s]; i2[s] = i1[s]; d1[s] = dist; i1[s] = col; }
                    else if (dist < d2[s]) { d2[s] = dist; i2[s] = col; }
                }
                acc[fr][fc] = (f32x4){0.f, 0.f, 0.f, 0.f};
            }
        }
    };

    STAGE(0);
    __syncthreads();
    #pragma unroll 2
    for (int t = 0; t < 256; ++t) {
        if (t < 255) STAGE(t + 1);
        COMPUTE(t);
        if ((t & 15) == 15) EPILOGUE(t >> 4);
        __syncthreads();
    }

    // intra-wave butterfly top-2 merge across the 16 column-lanes (per row slot)
    #pragma unroll
    for (int s = 0; s < 16; ++s) {
        #pragma unroll
        for (int off = 1; off < 16; off <<= 1) {
            float od1 = __shfl_xor(d1[s], off, 16);
            int   oi1 = __shfl_xor(i1[s], off, 16);
            float od2 = __shfl_xor(d2[s], off, 16);
            int   oi2 = __shfl_xor(i2[s], off, 16);
            bool rep = (od1 < d1[s]) || (od1 == d1[s] && oi1 < i1[s]);
            if (rep) {
                float nd2 = (d1[s] < od2) ? d1[s] : od2;
                int   ni2 = (d1[s] < od2) ? i1[s] : oi2;
                d2[s] = nd2; i2[s] = ni2; d1[s] = od1; i1[s] = oi1;
            } else if (od1 < d2[s]) { d2[s] = od1; i2[s] = oi1; }
        }
    }
    // lane (lane&15)==s owns slot s; static-unrolled select (rule #20)
    float md1 = 0.f, md2 = 0.f; int mi1 = 0, mi2 = 0;
    #pragma unroll
    for (int s = 0; s < 16; ++s) {
        bool mine = (lane & 15) == s;
        md1 = mine ? d1[s] : md1; mi1 = mine ? i1[s] : mi1;
        md2 = mine ? d2[s] : md2; mi2 = mine ? i2[s] : mi2;
    }
    int sl = lane & 15;
    int rowl = wr * 64 + (sl >> 2) * 16 + (lane >> 4) * 4 + (sl & 3);
    float4* mslot = (float4*)smem + rowl * 2 + wc;
    *mslot = make_float4(md1, __int_as_float(mi1), md2, __int_as_float(mi2));
    __syncthreads();
    if (tid < 128) {
        float4 e0 = ((float4*)smem)[tid * 2 + 0];
        float4 e1 = ((float4*)smem)[tid * 2 + 1];
        float a1 = e0.x, a2 = e0.z; int j1 = __float_as_int(e0.y), j2 = __float_as_int(e0.w);
        float b1 = e1.x, b2 = e1.z; int q1 = __float_as_int(e1.y), q2 = __float_as_int(e1.w);
        float D1, D2; int I1, I2;
        if (a1 <= b1) { D1 = a1; I1 = j1; if (b1 < a2) { D2 = b1; I2 = q1; } else { D2 = a2; I2 = j2; } }
        else          { D1 = b1; I1 = q1; if (a1 < b2) { D2 = a1; I2 = j1; } else { D2 = b2; I2 = q2; } }
        int row = rb * 128 + tid;
        idxo[row]   = I1;
        cand2o[row] = (D2 - D1 < MARGIN) ? I2 : -1;
    }
}

// ---------------- kernel 4: fp64 refinement of near-tie rows ----------------
__global__ __launch_bounds__(256) void k_refine(const float* __restrict__ x,
                                                const float* __restrict__ w,
                                                int* __restrict__ idxo,
                                                const int* __restrict__ cand2o) {
    int wid = threadIdx.x >> 6, lane = threadIdx.x & 63;
    int n = blockIdx.x * 4 + wid;
    int c2 = cand2o[n];
    if (c2 < 0) return;
    int c1 = idxo[n];
    const float* xr = x + (size_t)n * DIM;
    const float* w1 = w + (size_t)c1 * DIM;
    const float* w2 = w + (size_t)c2 * DIM;
    double s1 = 0.0, s2 = 0.0;
    #pragma unroll
    for (int j = 0; j < DIM / 64; ++j) {
        int d = lane + 64 * j;
        double xv = (double)xr[d];
        double a = (double)w1[d], b = (double)w2[d];
        s1 += a * a - 2.0 * xv * a;
        s2 += b * b - 2.0 * xv * b;
    }
    #pragma unroll
    for (int off = 32; off; off >>= 1) { s1 += __shfl_xor(s1, off, 64); s2 += __shfl_xor(s2, off, 64); }
    if (lane == 0) {
        int winner = (s2 < s1 || (s2 == s1 && c2 < c1)) ? c2 : c1;
        idxo[n] = winner;
    }
}

// ---------------- kernel 5: gather + loss partials + histogram + index out ----------------
__global__ __launch_bounds__(256) void k_gather(const float* __restrict__ x,
                                                const float* __restrict__ w,
                                                const int* __restrict__ idxo,
                                                float* __restrict__ out,
                                                int* __restrict__ hist,
                                                float* __restrict__ lossp) {
    int wid = threadIdx.x >> 6, lane = threadIdx.x & 63;
    int n = blockIdx.x * 4 + wid;
    int c = idxo[n];
    const float* wq = w + (size_t)c * DIM;
    const float* xq = x + (size_t)n * DIM;
    float* oq = out + 1 + (size_t)n * DIM;
    float s = 0.f;
    #pragma unroll
    for (int j = 0; j < DIM / 64; ++j) {
        int d = j * 64 + lane;
        float qv = wq[d];
        float dv = qv - xq[d];
        oq[d] = qv;
        s = fmaf(dv, dv, s);
    }
    #pragma unroll
    for (int off = 32; off; off >>= 1) s += __shfl_xor(s, off, 64);
    if (lane == 0) {
        lossp[n] = s;
        atomicAdd(&hist[c], 1);
        out[2 + NDTOT + n] = (float)c;
    }
}

// ---------------- kernel 6: deterministic finalize ----------------
__global__ __launch_bounds__(256) void k_finalize(const float* __restrict__ lossp,
                                                  const int* __restrict__ hist,
                                                  float* __restrict__ out) {
    __shared__ double sm[256];
    int t = threadIdx.x;
    double s = 0.0;
    for (int i = t; i < NROWS; i += 256) s += (double)lossp[i];
    sm[t] = s; __syncthreads();
    for (int off = 128; off; off >>= 1) { if (t < off) sm[t] += sm[t + off]; __syncthreads(); }
    if (t == 0) out[0] = (float)(sm[0] * 0.25 / (double)NDTOT);
    __syncthreads();
    double e = 0.0;
    for (int k = t; k < KCODES; k += 256) {
        double p = (double)hist[k] / (double)NROWS;
        e -= p * log(p + 1e-10);
    }
    sm[t] = e; __syncthreads();
    for (int off = 128; off; off >>= 1) { if (t < off) sm[t] += sm[t + off]; __syncthreads(); }
    if (t == 0) out[1 + NDTOT] = (float)exp(sm[0]);
}

extern "C" void kernel_launch(void* const* d_in, const int* in_sizes, int n_in,
                              void* d_out, int out_size, void* d_ws, size_t ws_size,
                              hipStream_t stream) {
    const float* x = (const float*)d_in[0];   // [64,1024,512] fp32
    const float* w = (const float*)d_in[1];   // [2048,512] fp32
    float* out = (float*)d_out;
    char* ws = (char*)d_ws;

    // xp (128 MB, bf16 hi/lo planes) lives in the d_out region starting at
    // out[4]: k_gemm consumes it before k_gather/k_finalize overwrite every
    // byte of that region with the real outputs (verified: quantized covers
    // out[1..NDTOT], perplexity out[1+NDTOT], indices out[2+NDTOT..]).
    char* xp = (char*)d_out + 16;

    char*  wp    = ws;                            // 4 MB
    float* wnorm = (float*)(ws + 4194304);        // 8 KB
    int*   idxo  = (int*)(ws + 4202496);          // 256 KB
    int*   cand2 = (int*)(ws + 4464640);          // 256 KB
    int*   hist  = (int*)(ws + 4726784);          // 8 KB
    float* lossp = (float*)(ws + 4734976);        // 256 KB

    hipMemsetAsync(hist, 0, KCODES * sizeof(int), stream);
    k_wnorm  <<<KCODES / 4, 256, 0, stream>>>(w, wnorm);
    k_prep   <<<(NROWS * 64) / 256, 256, 0, stream>>>(x, xp);
    k_prep   <<<(KCODES * 64) / 256, 256, 0, stream>>>(w, wp);
    k_gemm   <<<NROWS / 128, 256, 0, stream>>>(xp, wp, wnorm, idxo, cand2);
    k_refine <<<NROWS / 4, 256, 0, stream>>>(x, w, idxo, cand2);
    k_gather <<<NROWS / 4, 256, 0, stream>>>(x, w, idxo, out, hist, lossp);
    k_finalize<<<1, 256, 0, stream>>>(lossp, hist, out);
}

// Round 4
// 564.034 us; speedup vs baseline: 5.2314x; 1.0886x over previous
//
#include <hip/hip_runtime.h>
#include <cmath>

#define NROWS  65536
#define DIM    512
#define KCODES 2048
#define NDTOT  33554432LL   // NROWS*DIM
#define MARGIN 0.0625f

typedef __attribute__((ext_vector_type(8))) short short8;   // 8 bf16 = 1 MFMA operand
typedef __attribute__((ext_vector_type(4))) float f32x4;

// round-to-nearest-even float -> bf16 (bit version)
__device__ inline unsigned int f2bf(float x) {
    unsigned int u = __float_as_uint(x);
    return (u + 0x7FFFu + ((u >> 16) & 1u)) >> 16;
}

__device__ inline void gll16(const void* g, void* l) {
    __builtin_amdgcn_global_load_lds(
        (const __attribute__((address_space(1))) void*)g,
        (__attribute__((address_space(3))) void*)l, 16, 0, 0);
}

// ---------------- kernel 1: fp32 -> bf16 hi/lo planes in fragment-lane order,
// fused with row squared-norm (wave per row: 64 lanes x 8 elems = 512).
// tile layout (per rowblock rb of 128 rows, per ks of 32 k): 16384 bytes:
//   [plane 2][frow 8][lane 64][16B]   where lane = ((k%32)/8)*16 + (row%16),
//   frow = (row%128)/16, bytes r = k%8. Matches mfma_f32_16x16x32_bf16 A/B frags
//   (lane l holds row l&15, k = (l>>4)*8 + r).
__global__ __launch_bounds__(256) void k_prep(const float* __restrict__ src,
                                              char* __restrict__ dst,
                                              float* __restrict__ norms) {
    long gid = (long)blockIdx.x * 256 + threadIdx.x;
    int row = (int)(gid >> 6);
    int k8  = (int)(gid & 63);           // chunk of 8 k-values
    const float4* s = (const float4*)(src + (size_t)row * DIM + k8 * 8);
    float4 v0 = s[0], v1 = s[1];
    float vv[8] = {v0.x, v0.y, v0.z, v0.w, v1.x, v1.y, v1.z, v1.w};
    unsigned int hiw[4], low[4];
    float nrm = 0.f;
    #pragma unroll
    for (int j = 0; j < 4; ++j) {
        unsigned int h0 = f2bf(vv[2*j]), h1 = f2bf(vv[2*j+1]);
        float hf0 = __uint_as_float(h0 << 16), hf1 = __uint_as_float(h1 << 16);
        unsigned int l0 = f2bf(vv[2*j] - hf0), l1 = f2bf(vv[2*j+1] - hf1);
        hiw[j] = h0 | (h1 << 16);
        low[j] = l0 | (l1 << 16);
        nrm = fmaf(vv[2*j], vv[2*j], nrm);
        nrm = fmaf(vv[2*j+1], vv[2*j+1], nrm);
    }
    int rb = row >> 7, frow = (row >> 4) & 7;
    int ks = k8 >> 2, sub = k8 & 3;
    int l  = sub * 16 + (row & 15);
    size_t off = (size_t)(rb * 16 + ks) * 16384 + (size_t)frow * 1024 + (size_t)l * 16;
    *(uint4*)(dst + off)        = make_uint4(hiw[0], hiw[1], hiw[2], hiw[3]);
    *(uint4*)(dst + off + 8192) = make_uint4(low[0], low[1], low[2], low[3]);
    #pragma unroll
    for (int off2 = 32; off2; off2 >>= 1) nrm += __shfl_xor(nrm, off2, 64);
    if ((threadIdx.x & 63) == 0) norms[row] = nrm;
}

// ---------------- kernel 2: split-bf16 MFMA GEMM + fused top-2 argmin ----------------
// 512 blocks (2 resident/CU at 64KB LDS), 4 waves of 64x64 output,
// cb-outer (16 x 128 codes), ks-inner (16 x K=32), 2-deep dbuf pipeline with
// COUNTED vmcnt (T4): stage t+1's 8 loads stay in flight across the barrier;
// only tile-t's batch is drained. Raw s_barrier (no compiler vmcnt(0) drain).
__global__ __launch_bounds__(256, 2) void k_gemm(const char* __restrict__ xp,
                                                 const char* __restrict__ wp,
                                                 const float* __restrict__ wnorm,
                                                 int* __restrict__ idxo,
                                                 int* __restrict__ cand2o,
                                                 float* __restrict__ bestd) {
    __shared__ char smem[65536];   // As[2] @0,16384 ; Bs[2] @32768,49152
    const int tid = threadIdx.x;
    const int lane = tid & 63;
    const int wid = tid >> 6;
    const int wr = wid >> 1, wc = wid & 1;
    const int rb = blockIdx.x;
    const char* xsrc = xp + (size_t)rb * (16 * 16384);

    f32x4 acc[4][4];
    #pragma unroll
    for (int i = 0; i < 4; ++i)
        #pragma unroll
        for (int j = 0; j < 4; ++j) acc[i][j] = (f32x4){0.f, 0.f, 0.f, 0.f};

    float d1[16], d2[16]; int i1[16], i2[16];
    #pragma unroll
    for (int s = 0; s < 16; ++s) { d1[s] = d2[s] = 3.4e38f; i1[s] = i2[s] = 0; }

    auto STAGE = [&](int t) {
        int cb = t >> 4, ks = t & 15, p = t & 1;
        const char* bsrc = wp + (size_t)(cb * 16 + ks) * 16384;
        const char* asrc = xsrc + (size_t)ks * 16384;
        char* bdst = smem + 32768 + p * 16384;
        char* adst = smem + p * 16384;
        #pragma unroll
        for (int i = 0; i < 4; ++i) {
            int c = wid * 4 + i;   // 16 chunks of 1024B each, 4 per wave
            gll16(bsrc + c * 1024 + lane * 16, bdst + c * 1024);
            gll16(asrc + c * 1024 + lane * 16, adst + c * 1024);
        }
    };

    auto COMPUTE = [&](int t) {
        int p = t & 1;
        const char* A = smem + p * 16384;
        const char* B = smem + 32768 + p * 16384;
        short8 ah[4], al[4];
        #pragma unroll
        for (int fr = 0; fr < 4; ++fr) {
            int frow = wr * 4 + fr;
            ah[fr] = *(const short8*)(A + frow * 1024 + lane * 16);
            al[fr] = *(const short8*)(A + 8192 + frow * 1024 + lane * 16);
        }
        #pragma unroll
        for (int fc = 0; fc < 4; ++fc) {
            int fcol = wc * 4 + fc;
            short8 bh = *(const short8*)(B + fcol * 1024 + lane * 16);
            short8 bl = *(const short8*)(B + 8192 + fcol * 1024 + lane * 16);
            #pragma unroll
            for (int fr = 0; fr < 4; ++fr) {
                acc[fr][fc] = __builtin_amdgcn_mfma_f32_16x16x32_bf16(ah[fr], bh, acc[fr][fc], 0, 0, 0);
                acc[fr][fc] = __builtin_amdgcn_mfma_f32_16x16x32_bf16(ah[fr], bl, acc[fr][fc], 0, 0, 0);
                acc[fr][fc] = __builtin_amdgcn_mfma_f32_16x16x32_bf16(al[fr], bh, acc[fr][fc], 0, 0, 0);
            }
        }
    };

    auto EPILOGUE = [&](int cb) {
        #pragma unroll
        for (int fc = 0; fc < 4; ++fc) {
            int col = cb * 128 + wc * 64 + fc * 16 + (lane & 15);
            float wn = wnorm[col];
            #pragma unroll
            for (int fr = 0; fr < 4; ++fr) {
                #pragma unroll
                for (int reg = 0; reg < 4; ++reg) {
                    float dist = fmaf(-2.f, acc[fr][fc][reg], wn);
                    int s = fr * 4 + reg;
                    if (dist < d1[s]) { d2[s] = d1[s]; i2[s] = i1[s]; d1[s] = dist; i1[s] = col; }
                    else if (dist < d2[s]) { d2[s] = dist; i2[s] = col; }
                }
                acc[fr][fc] = (f32x4){0.f, 0.f, 0.f, 0.f};
            }
        }
    };

    STAGE(0);
    #pragma unroll 2
    for (int t = 0; t < 256; ++t) {
        if (t < 255) {
            STAGE(t + 1);
            asm volatile("s_waitcnt vmcnt(8)" ::: "memory");   // drain tile-t batch only
        } else {
            asm volatile("s_waitcnt vmcnt(0)" ::: "memory");
        }
        asm volatile("s_barrier" ::: "memory");                // data for t ready everywhere
        COMPUTE(t);
        if ((t & 15) == 15) EPILOGUE(t >> 4);
        asm volatile("s_barrier" ::: "memory");                // all reads of buf[t&1] done
    }

    // intra-wave butterfly top-2 merge across the 16 column-lanes (per row slot)
    #pragma unroll
    for (int s = 0; s < 16; ++s) {
        #pragma unroll
        for (int off = 1; off < 16; off <<= 1) {
            float od1 = __shfl_xor(d1[s], off, 16);
            int   oi1 = __shfl_xor(i1[s], off, 16);
            float od2 = __shfl_xor(d2[s], off, 16);
            int   oi2 = __shfl_xor(i2[s], off, 16);
            bool rep = (od1 < d1[s]) || (od1 == d1[s] && oi1 < i1[s]);
            if (rep) {
                float nd2 = (d1[s] < od2) ? d1[s] : od2;
                int   ni2 = (d1[s] < od2) ? i1[s] : oi2;
                d2[s] = nd2; i2[s] = ni2; d1[s] = od1; i1[s] = oi1;
            } else if (od1 < d2[s]) { d2[s] = od1; i2[s] = oi1; }
        }
    }
    // lane (lane&15)==s owns slot s; static-unrolled select (rule #20)
    float md1 = 0.f, md2 = 0.f; int mi1 = 0, mi2 = 0;
    #pragma unroll
    for (int s = 0; s < 16; ++s) {
        bool mine = (lane & 15) == s;
        md1 = mine ? d1[s] : md1; mi1 = mine ? i1[s] : mi1;
        md2 = mine ? d2[s] : md2; mi2 = mine ? i2[s] : mi2;
    }
    int sl = lane & 15;
    int rowl = wr * 64 + (sl >> 2) * 16 + (lane >> 4) * 4 + (sl & 3);
    float4* mslot = (float4*)smem + rowl * 2 + wc;   // first 4KB = As buf0, dead now
    *mslot = make_float4(md1, __int_as_float(mi1), md2, __int_as_float(mi2));
    __syncthreads();
    if (tid < 128) {
        float4 e0 = ((float4*)smem)[tid * 2 + 0];
        float4 e1 = ((float4*)smem)[tid * 2 + 1];
        float a1 = e0.x, a2 = e0.z; int j1 = __float_as_int(e0.y), j2 = __float_as_int(e0.w);
        float b1 = e1.x, b2 = e1.z; int q1 = __float_as_int(e1.y), q2 = __float_as_int(e1.w);
        float D1, D2; int I1, I2;
        if (a1 <= b1) { D1 = a1; I1 = j1; if (b1 < a2) { D2 = b1; I2 = q1; } else { D2 = a2; I2 = j2; } }
        else          { D1 = b1; I1 = q1; if (a1 < b2) { D2 = a1; I2 = j1; } else { D2 = b2; I2 = q2; } }
        int row = rb * 128 + tid;
        idxo[row]   = I1;
        bestd[row]  = D1;
        cand2o[row] = (D2 - D1 < MARGIN) ? I2 : -1;
    }
}

// ---------------- kernel 3: fp64 refinement of near-tie rows ----------------
__global__ __launch_bounds__(256) void k_refine(const float* __restrict__ x,
                                                const float* __restrict__ w,
                                                int* __restrict__ idxo,
                                                const int* __restrict__ cand2o,
                                                float* __restrict__ bestd) {
    int wid = threadIdx.x >> 6, lane = threadIdx.x & 63;
    int n = blockIdx.x * 4 + wid;
    int c2 = cand2o[n];
    if (c2 < 0) return;
    int c1 = idxo[n];
    const float* xr = x + (size_t)n * DIM;
    const float* w1 = w + (size_t)c1 * DIM;
    const float* w2 = w + (size_t)c2 * DIM;
    double s1 = 0.0, s2 = 0.0;
    #pragma unroll
    for (int j = 0; j < DIM / 64; ++j) {
        int d = lane + 64 * j;
        double xv = (double)xr[d];
        double a = (double)w1[d], b = (double)w2[d];
        s1 += a * a - 2.0 * xv * a;
        s2 += b * b - 2.0 * xv * b;
    }
    #pragma unroll
    for (int off = 32; off; off >>= 1) { s1 += __shfl_xor(s1, off, 64); s2 += __shfl_xor(s2, off, 64); }
    if (lane == 0) {
        bool take2 = (s2 < s1) || (s2 == s1 && c2 < c1);
        idxo[n]  = take2 ? c2 : c1;
        bestd[n] = (float)(take2 ? s2 : s1);   // exact distance for loss
    }
}

// ---------------- kernel 4: gather + loss-from-distance + histogram + index out ----------------
__global__ __launch_bounds__(256) void k_gather(const float* __restrict__ w,
                                                const int* __restrict__ idxo,
                                                const float* __restrict__ bestd,
                                                const float* __restrict__ xnorm,
                                                float* __restrict__ out,
                                                int* __restrict__ hist,
                                                float* __restrict__ lossp) {
    int wid = threadIdx.x >> 6, lane = threadIdx.x & 63;
    int n = blockIdx.x * 4 + wid;
    int c = idxo[n];
    const float* wq = w + (size_t)c * DIM;
    float* oq = out + 1 + (size_t)n * DIM;   // quantized_st == quantized numerically
    #pragma unroll
    for (int j = 0; j < DIM / 64; ++j) {
        int d = j * 64 + lane;
        oq[d] = wq[d];
    }
    if (lane == 0) {
        // ||x-w||^2 = bestd + ||x||^2  (bestd = ||w||^2 - 2 x.w; fp64-exact for refined rows)
        lossp[n] = bestd[n] + xnorm[n];
        atomicAdd(&hist[c], 1);
        out[2 + NDTOT + n] = (float)c;
    }
}

// ---------------- kernel 5: deterministic finalize ----------------
__global__ __launch_bounds__(256) void k_finalize(const float* __restrict__ lossp,
                                                  const int* __restrict__ hist,
                                                  float* __restrict__ out) {
    __shared__ double sm[256];
    int t = threadIdx.x;
    double s = 0.0;
    const float4* lp4 = (const float4*)lossp;
    for (int i = t; i < NROWS / 4; i += 256) {
        float4 v = lp4[i];
        s += (double)v.x + (double)v.y + (double)v.z + (double)v.w;
    }
    sm[t] = s; __syncthreads();
    for (int off = 128; off; off >>= 1) { if (t < off) sm[t] += sm[t + off]; __syncthreads(); }
    if (t == 0) out[0] = (float)(sm[0] * 0.25 / (double)NDTOT);
    __syncthreads();
    double e = 0.0;
    for (int k = t; k < KCODES; k += 256) {
        double p = (double)hist[k] / (double)NROWS;
        e -= p * log(p + 1e-10);
    }
    sm[t] = e; __syncthreads();
    for (int off = 128; off; off >>= 1) { if (t < off) sm[t] += sm[t + off]; __syncthreads(); }
    if (t == 0) out[1 + NDTOT] = (float)exp(sm[0]);
}

extern "C" void kernel_launch(void* const* d_in, const int* in_sizes, int n_in,
                              void* d_out, int out_size, void* d_ws, size_t ws_size,
                              hipStream_t stream) {
    const float* x = (const float*)d_in[0];   // [64,1024,512] fp32
    const float* w = (const float*)d_in[1];   // [2048,512] fp32
    float* out = (float*)d_out;
    char* ws = (char*)d_ws;

    // xp (128 MB, bf16 hi/lo planes) lives in the d_out region starting at
    // out[4]: k_gemm consumes it before k_gather/k_finalize overwrite every
    // byte of that region with the real outputs.
    char* xp = (char*)d_out + 16;

    char*  wp    = ws;                            // 4 MB
    float* wnorm = (float*)(ws + 4194304);        // 8 KB
    int*   idxo  = (int*)(ws + 4202496);          // 256 KB
    int*   cand2 = (int*)(ws + 4464640);          // 256 KB
    int*   hist  = (int*)(ws + 4726784);          // 8 KB
    float* lossp = (float*)(ws + 4734976);        // 256 KB
    float* xnorm = (float*)(ws + 4997120);        // 256 KB
    float* bestd = (float*)(ws + 5259264);        // 256 KB

    hipMemsetAsync(hist, 0, KCODES * sizeof(int), stream);
    k_prep   <<<(KCODES * 64) / 256, 256, 0, stream>>>(w, wp, wnorm);
    k_prep   <<<(NROWS * 64) / 256, 256, 0, stream>>>(x, xp, xnorm);
    k_gemm   <<<NROWS / 128, 256, 0, stream>>>(xp, wp, wnorm, idxo, cand2, bestd);
    k_refine <<<NROWS / 4, 256, 0, stream>>>(x, w, idxo, cand2, bestd);
    k_gather <<<NROWS / 4, 256, 0, stream>>>(w, idxo, bestd, xnorm, out, hist, lossp);
    k_finalize<<<1, 256, 0, stream>>>(lossp, hist, out);
}